// Round 4
// baseline (438.865 us; speedup 1.0000x reference)
//
#include <hip/hip_runtime.h>
#include <hip/hip_bf16.h>
#include <math.h>

#define BN 4
#define HIq 128
#define WIq 128
#define DIM 128
#define HOq 64
#define WOq 64
#define NPOS 4096      // HO*WO
#define NTOK 16384     // HI*WI
#define EPS_LN 1e-5f
#define EPS_A 1e-6f

typedef __attribute__((ext_vector_type(8))) short bf16x8;
typedef __attribute__((ext_vector_type(4))) float f32x4;

__device__ __forceinline__ unsigned short f2bf(float f) {
    unsigned int u = __float_as_uint(f);
    u = (u + 0x7FFFu + ((u >> 16) & 1u)) >> 16;
    return (unsigned short)u;
}

__device__ __forceinline__ int nb_index(int h, int w, int t) {
    int ch = min(max(h, 1), HOq - 2);
    int cw = min(max(w, 1), WOq - 2);
    int dr = t / 3 - 1, dc = t % 3 - 1;
    return (ch + dr) * WOq + (cw + dc);
}

// ---------------------------------------------------------------------------
// x -> bf16, LN(x) -> bf16. Wave wv handles row blockIdx*4+wv.
__global__ void prep_ln_kernel(const float* __restrict__ x,
                               const float* __restrict__ g,
                               const float* __restrict__ bb,
                               unsigned short* __restrict__ x_bf,
                               unsigned short* __restrict__ xln_bf) {
    int tid = threadIdx.x, wv = tid >> 6, lane = tid & 63;
    long row = (long)blockIdx.x * 4 + wv;
    const float* xr = x + row * DIM;
    float v0 = xr[lane], v1 = xr[lane + 64];
    float s = v0 + v1, ss = v0 * v0 + v1 * v1;
    #pragma unroll
    for (int off = 32; off; off >>= 1) {
        s  += __shfl_xor(s, off, 64);
        ss += __shfl_xor(ss, off, 64);
    }
    float mu = s * (1.0f / DIM);
    float var = fmaxf(ss * (1.0f / DIM) - mu * mu, 0.0f);
    float rstd = rsqrtf(var + EPS_LN);
    x_bf[row * DIM + lane]        = f2bf(v0);
    x_bf[row * DIM + lane + 64]   = f2bf(v1);
    xln_bf[row * DIM + lane]      = f2bf((v0 - mu) * rstd * g[lane] + bb[lane]);
    xln_bf[row * DIM + lane + 64] = f2bf((v1 - mu) * rstd * g[lane + 64] + bb[lane + 64]);
}

// ---------------------------------------------------------------------------
// conv_w [O][I][3][3] -> wt [o][tap*128+i] bf16
__global__ void conv_wt_kernel(const float* __restrict__ cw, unsigned short* __restrict__ wt) {
    int o = blockIdx.x, tap = blockIdx.y, i = threadIdx.x;
    wt[(long)o * 1152 + tap * 128 + i] = f2bf(cw[((long)o * 128 + i) * 9 + tap]);
}

// k_w/v_w/q_w [i][o] -> [o][i] bf16 ; mlp_w1 -> [j][i] ; mlp_w2 -> [o][j]
__global__ void wt_all_kernel(const float* __restrict__ kw, const float* __restrict__ vw,
                              const float* __restrict__ qw,
                              const float* __restrict__ w1, const float* __restrict__ w2,
                              unsigned short* __restrict__ kwt, unsigned short* __restrict__ vwt,
                              unsigned short* __restrict__ qwt,
                              unsigned short* __restrict__ w1t, unsigned short* __restrict__ w2t) {
    int o = blockIdx.x, i = threadIdx.x;
    kwt[o * DIM + i] = f2bf(kw[i * DIM + o]);
    vwt[o * DIM + i] = f2bf(vw[i * DIM + o]);
    qwt[o * DIM + i] = f2bf(qw[i * DIM + o]);
    w1t[(2 * o) * DIM + i]     = f2bf(w1[i * 256 + 2 * o]);
    w1t[(2 * o + 1) * DIM + i] = f2bf(w1[i * 256 + 2 * o + 1]);
    w2t[o * 256 + i]       = f2bf(w2[i * DIM + o]);
    w2t[o * 256 + 128 + i] = f2bf(w2[(128 + i) * DIM + o]);
}

// ---------------------------------------------------------------------------
// Conv as implicit-im2col MFMA GEMM.
__global__ __launch_bounds__(256) void conv_mfma_kernel(
        const unsigned short* __restrict__ x_bf,
        const unsigned short* __restrict__ wt,
        float* __restrict__ seed) {
    __shared__ unsigned short As[64][40];
    __shared__ unsigned short Bs[128][40];
    int tid = threadIdx.x;
    int wv = tid >> 6, lane = tid & 63;
    int quad = lane >> 4, l15 = lane & 15;
    int wr = wv >> 1, wc = wv & 1;
    int b = blockIdx.x >> 6, ho = blockIdx.x & 63;

    f32x4 acc[2][4];
    #pragma unroll
    for (int mt = 0; mt < 2; ++mt)
        #pragma unroll
        for (int nt = 0; nt < 4; ++nt) acc[mt][nt] = (f32x4){0.f, 0.f, 0.f, 0.f};

    int m = tid >> 2, seg = tid & 3;
    for (int tap = 0; tap < 9; ++tap) {
        int kh = tap / 3, kw = tap % 3;
        int hi = 2 * ho - 1 + kh;
        int wi = 2 * m - 1 + kw;
        bool ok = (hi >= 0) && (hi < HIq) && (wi >= 0) && (wi < WIq);
        long arow = (((long)b * HIq + hi) * WIq + wi) * DIM;
        #pragma unroll
        for (int ib = 0; ib < 4; ++ib) {
            __syncthreads();
            int4 av = {0, 0, 0, 0};
            if (ok) av = *(const int4*)(x_bf + arow + ib * 32 + seg * 8);
            *(int4*)&As[m][seg * 8] = av;
            #pragma unroll
            for (int r2 = 0; r2 < 2; ++r2) {
                int lin = r2 * 256 + tid;
                int n = lin >> 2, sg = lin & 3;
                *(int4*)&Bs[n][sg * 8] =
                    *(const int4*)(wt + (long)n * 1152 + tap * 128 + ib * 32 + sg * 8);
            }
            __syncthreads();
            bf16x8 afr[2], bfr[4];
            #pragma unroll
            for (int mt = 0; mt < 2; ++mt)
                afr[mt] = *(bf16x8*)&As[wr * 32 + mt * 16 + l15][quad * 8];
            #pragma unroll
            for (int nt = 0; nt < 4; ++nt)
                bfr[nt] = *(bf16x8*)&Bs[wc * 64 + nt * 16 + l15][quad * 8];
            #pragma unroll
            for (int mt = 0; mt < 2; ++mt)
                #pragma unroll
                for (int nt = 0; nt < 4; ++nt)
                    acc[mt][nt] = __builtin_amdgcn_mfma_f32_16x16x32_bf16(
                        afr[mt], bfr[nt], acc[mt][nt], 0, 0, 0);
        }
    }
    long outb = ((long)b * NPOS + ho * WOq) * DIM;
    #pragma unroll
    for (int mt = 0; mt < 2; ++mt)
        #pragma unroll
        for (int r = 0; r < 4; ++r) {
            int wo = wr * 32 + mt * 16 + quad * 4 + r;
            #pragma unroll
            for (int nt = 0; nt < 4; ++nt) {
                int col = wc * 64 + nt * 16 + l15;
                seed[outb + (long)wo * DIM + col] = acc[mt][nt][r];
            }
        }
}

// ---------------------------------------------------------------------------
// kv dual MFMA GEMM.
__global__ __launch_bounds__(256) void kv_mfma_kernel(
        const unsigned short* __restrict__ x_bf,
        const unsigned short* __restrict__ xln_bf,
        const unsigned short* __restrict__ kwt,
        const unsigned short* __restrict__ vwt,
        float* __restrict__ k_g, float* __restrict__ v_g) {
    __shared__ unsigned short Ak[64][40], Av[64][40];
    __shared__ unsigned short Bk[128][40], Bv[128][40];
    int tid = threadIdx.x;
    int wv = tid >> 6, lane = tid & 63;
    int quad = lane >> 4, l15 = lane & 15;
    int wr = wv >> 1, wc = wv & 1;
    long tokBase = (long)blockIdx.x * 64;

    f32x4 acck[2][4], accv[2][4];
    #pragma unroll
    for (int mt = 0; mt < 2; ++mt)
        #pragma unroll
        for (int nt = 0; nt < 4; ++nt) {
            acck[mt][nt] = (f32x4){0.f, 0.f, 0.f, 0.f};
            accv[mt][nt] = (f32x4){0.f, 0.f, 0.f, 0.f};
        }

    int m = tid >> 2, seg = tid & 3;
    #pragma unroll
    for (int ib = 0; ib < 4; ++ib) {
        __syncthreads();
        *(int4*)&Ak[m][seg * 8] = *(const int4*)(xln_bf + (tokBase + m) * DIM + ib * 32 + seg * 8);
        *(int4*)&Av[m][seg * 8] = *(const int4*)(x_bf   + (tokBase + m) * DIM + ib * 32 + seg * 8);
        #pragma unroll
        for (int r2 = 0; r2 < 2; ++r2) {
            int lin = r2 * 256 + tid;
            int n = lin >> 2, sg = lin & 3;
            *(int4*)&Bk[n][sg * 8] = *(const int4*)(kwt + (long)n * DIM + ib * 32 + sg * 8);
            *(int4*)&Bv[n][sg * 8] = *(const int4*)(vwt + (long)n * DIM + ib * 32 + sg * 8);
        }
        __syncthreads();
        bf16x8 ak[2], av2[2], bk[4], bv[4];
        #pragma unroll
        for (int mt = 0; mt < 2; ++mt) {
            ak[mt]  = *(bf16x8*)&Ak[wr * 32 + mt * 16 + l15][quad * 8];
            av2[mt] = *(bf16x8*)&Av[wr * 32 + mt * 16 + l15][quad * 8];
        }
        #pragma unroll
        for (int nt = 0; nt < 4; ++nt) {
            bk[nt] = *(bf16x8*)&Bk[wc * 64 + nt * 16 + l15][quad * 8];
            bv[nt] = *(bf16x8*)&Bv[wc * 64 + nt * 16 + l15][quad * 8];
        }
        #pragma unroll
        for (int mt = 0; mt < 2; ++mt)
            #pragma unroll
            for (int nt = 0; nt < 4; ++nt) {
                acck[mt][nt] = __builtin_amdgcn_mfma_f32_16x16x32_bf16(ak[mt],  bk[nt], acck[mt][nt], 0, 0, 0);
                accv[mt][nt] = __builtin_amdgcn_mfma_f32_16x16x32_bf16(av2[mt], bv[nt], accv[mt][nt], 0, 0, 0);
            }
    }
    #pragma unroll
    for (int mt = 0; mt < 2; ++mt)
        #pragma unroll
        for (int r = 0; r < 4; ++r) {
            long tok = tokBase + wr * 32 + mt * 16 + quad * 4 + r;
            int b = (int)(tok >> 14);
            int pix = (int)(tok & 16383);
            int ih = pix >> 7, iw = pix & 127;
            int g = (ih & 1) * 2 + (iw & 1);
            int pos = (ih >> 1) * WOq + (iw >> 1);
            long base = ((long)(b * 4 + g) * NPOS + pos) * DIM;
            #pragma unroll
            for (int nt = 0; nt < 4; ++nt) {
                int col = wc * 64 + nt * 16 + l15;
                k_g[base + col] = acck[mt][nt][r];
                v_g[base + col] = accv[mt][nt][r];
            }
        }
}

// ---------------------------------------------------------------------------
__global__ void ln_kernel(const float* __restrict__ in, float* __restrict__ out,
                          const float* __restrict__ g, const float* __restrict__ bb) {
    int row = blockIdx.x, tid = threadIdx.x;
    float v = in[(long)row * DIM + tid];
    float s = v, ss = v * v;
    int lane = tid & 63, wv = tid >> 6;
    #pragma unroll
    for (int off = 32; off; off >>= 1) {
        s  += __shfl_xor(s, off, 64);
        ss += __shfl_xor(ss, off, 64);
    }
    __shared__ float red[4];
    if (lane == 0) { red[wv] = s; red[2 + wv] = ss; }
    __syncthreads();
    float S = red[0] + red[1], SS = red[2] + red[3];
    float mu = S * (1.0f / DIM);
    float var = fmaxf(SS * (1.0f / DIM) - mu * mu, 0.0f);
    float rstd = rsqrtf(var + EPS_LN);
    out[(long)row * DIM + tid] = (v - mu) * rstd * g[tid] + bb[tid];
}

// ---------------------------------------------------------------------------
// q = LN(x_out)@q_w via MFMA. 16 tokens/block, 1024 blocks.
__global__ __launch_bounds__(256) void q_mfma_kernel(
        const float* __restrict__ x_out,
        const unsigned short* __restrict__ qwt,
        const float* __restrict__ ln_g, const float* __restrict__ ln_b,
        float* __restrict__ q) {
    __shared__ unsigned short sxbf[16][136];
    int tid = threadIdx.x;
    long base = (long)blockIdx.x * 16;
    int wv = tid >> 6, lane = tid & 63;
    int quad = lane >> 4, l15 = lane & 15;

    // stage: LN(x_out) -> bf16. 16 threads/row, 8 contiguous cols each.
    {
        int r = tid >> 4, seg = tid & 15;
        const float* xr = x_out + (base + r) * DIM + seg * 8;
        float4 a = *(const float4*)xr;
        float4 c = *(const float4*)(xr + 4);
        float s  = a.x + a.y + a.z + a.w + c.x + c.y + c.z + c.w;
        float ss = a.x*a.x + a.y*a.y + a.z*a.z + a.w*a.w
                 + c.x*c.x + c.y*c.y + c.z*c.z + c.w*c.w;
        #pragma unroll
        for (int off = 1; off < 16; off <<= 1) {
            s  += __shfl_xor(s, off, 64);
            ss += __shfl_xor(ss, off, 64);
        }
        float mu = s * (1.0f / DIM);
        float var = fmaxf(ss * (1.0f / DIM) - mu * mu, 0.0f);
        float rstd = rsqrtf(var + EPS_LN);
        float4 g0 = *(const float4*)(ln_g + seg * 8);
        float4 g1 = *(const float4*)(ln_g + seg * 8 + 4);
        float4 b0 = *(const float4*)(ln_b + seg * 8);
        float4 b1v = *(const float4*)(ln_b + seg * 8 + 4);
        unsigned short u[8] = {
            f2bf((a.x - mu) * rstd * g0.x + b0.x),
            f2bf((a.y - mu) * rstd * g0.y + b0.y),
            f2bf((a.z - mu) * rstd * g0.z + b0.z),
            f2bf((a.w - mu) * rstd * g0.w + b0.w),
            f2bf((c.x - mu) * rstd * g1.x + b1v.x),
            f2bf((c.y - mu) * rstd * g1.y + b1v.y),
            f2bf((c.z - mu) * rstd * g1.z + b1v.z),
            f2bf((c.w - mu) * rstd * g1.w + b1v.w)};
        *(int4*)&sxbf[r][seg * 8] = *(int4*)u;
    }
    __syncthreads();

    // GEMM: M=16, N=128 (wave -> 32 cols), K=128
    f32x4 acc[2];
    acc[0] = (f32x4){0.f, 0.f, 0.f, 0.f};
    acc[1] = (f32x4){0.f, 0.f, 0.f, 0.f};
    #pragma unroll
    for (int kb = 0; kb < 4; ++kb) {
        bf16x8 afr = *(bf16x8*)&sxbf[l15][kb * 32 + quad * 8];
        #pragma unroll
        for (int nt = 0; nt < 2; ++nt) {
            int n = wv * 32 + nt * 16 + l15;
            bf16x8 bfr = *(const bf16x8*)(qwt + (long)n * DIM + kb * 32 + quad * 8);
            acc[nt] = __builtin_amdgcn_mfma_f32_16x16x32_bf16(afr, bfr, acc[nt], 0, 0, 0);
        }
    }
    #pragma unroll
    for (int r = 0; r < 4; ++r) {
        long tok = base + quad * 4 + r;
        #pragma unroll
        for (int nt = 0; nt < 2; ++nt) {
            int col = wv * 32 + nt * 16 + l15;
            q[tok * DIM + col] = acc[nt][r];
        }
    }
}

// ---------------------------------------------------------------------------
__global__ void zero_kernel(float* __restrict__ p, int n) {
    int i = blockIdx.x * blockDim.x + threadIdx.x;
    if (i < n) p[i] = 0.0f;
}

// ---------------------------------------------------------------------------
__global__ void attn_kernel(const float* __restrict__ k_g,
                            const float* __restrict__ q,
                            const float* __restrict__ rpb,
                            const float* __restrict__ tau,
                            float* __restrict__ attn_out,
                            float* __restrict__ col_sums) {
    int tid = threadIdx.x;
    int wv = tid >> 6, lane = tid & 63;
    int cell = blockIdx.x * 4 + wv;
    int b = cell >> 14;
    int rem = cell & 16383;
    int g = rem >> 12;
    int pos = rem & 4095;
    int h = pos >> 6, w = pos & 63;

    const float2* kp = (const float2*)(k_g + (long)cell * DIM);
    float2 kv2 = kp[lane];
    float scale = expf(tau[0]);

    float l[9];
    #pragma unroll
    for (int t = 0; t < 9; ++t) {
        int n = nb_index(h, w, t);
        const float2* qp = (const float2*)(q + ((long)b * NPOS + n) * DIM);
        float2 qv = qp[lane];
        float p = kv2.x * qv.x + kv2.y * qv.y;
        #pragma unroll
        for (int off = 32; off; off >>= 1) p += __shfl_xor(p, off, 64);
        l[t] = (p + rpb[g * 9 + t]) * scale;
    }
    float m = l[0];
    #pragma unroll
    for (int t = 1; t < 9; ++t) m = fmaxf(m, l[t]);
    float e[9], s = 0.f;
    #pragma unroll
    for (int t = 0; t < 9; ++t) { e[t] = __expf(l[t] - m); s += e[t]; }
    float inv = 1.0f / s;

    float myv = 0.f; int myn = 0;
    #pragma unroll
    for (int t = 0; t < 9; ++t) {
        float a = e[t] * inv + EPS_A;
        if (lane == t) { myv = a; myn = nb_index(h, w, t); }
    }
    if (lane < 9) {
        attn_out[(long)cell * 9 + lane] = myv;
        atomicAdd(&col_sums[b * NPOS + myn], myv);
    }
}

// ---------------------------------------------------------------------------
__global__ void acol_upd_kernel(const float* __restrict__ attn_out,
                                const float* __restrict__ col_sums,
                                const float* __restrict__ v_g,
                                float* __restrict__ acol_out,
                                float* __restrict__ x_out) {
    __shared__ float sA[36];
    int tid = threadIdx.x;
    int row = blockIdx.x;
    int b = row >> 12, pos = row & 4095;
    int h = pos >> 6, w = pos & 63;

    if (tid < 36) {
        int g = tid / 9, t = tid % 9;
        long ci = ((long)(b * 4 + g) * NPOS + pos) * 9 + t;
        float a = attn_out[ci];
        float cs = col_sums[b * NPOS + nb_index(h, w, t)];
        float A = a / (cs + 1e-8f);
        sA[tid] = A;
        acol_out[ci] = A;
    }
    __syncthreads();

    int nn[9];
    #pragma unroll
    for (int t = 0; t < 9; ++t) nn[t] = nb_index(h, w, t);

    float acc = 0.f;
    #pragma unroll
    for (int g = 0; g < 4; ++g) {
        const float* vb = v_g + (long)(b * 4 + g) * NPOS * DIM;
        #pragma unroll
        for (int t = 0; t < 9; ++t) {
            acc += sA[g * 9 + t] * vb[(long)nn[t] * DIM + tid];
        }
    }
    x_out[(long)row * DIM + tid] += acc;
}

// ---------------------------------------------------------------------------
// Fused MFMA MLP v2: 16 tokens/block, 1024 blocks.
__global__ __launch_bounds__(256) void mlp_mfma_kernel(
        float* __restrict__ x_out,
        const unsigned short* __restrict__ w1t,  // [256][128]
        const unsigned short* __restrict__ w2t,  // [128][256]
        const float* __restrict__ b1, const float* __restrict__ b2,
        const float* __restrict__ ln_g, const float* __restrict__ ln_b) {
    __shared__ unsigned short sxbf[16][136];
    __shared__ unsigned short h_s[16][264];
    __shared__ float o_s[16][132];
    int tid = threadIdx.x;
    long base = (long)blockIdx.x * 16;
    int wv = tid >> 6, lane = tid & 63;
    int quad = lane >> 4, l15 = lane & 15;
    int r16 = tid >> 4, seg = tid & 15;

    // stage x -> bf16 (coalesced: 16 threads/row, 8 cols each)
    {
        const float* xr = x_out + (base + r16) * DIM + seg * 8;
        float4 a = *(const float4*)xr;
        float4 c = *(const float4*)(xr + 4);
        unsigned short u[8] = {f2bf(a.x), f2bf(a.y), f2bf(a.z), f2bf(a.w),
                               f2bf(c.x), f2bf(c.y), f2bf(c.z), f2bf(c.w)};
        *(int4*)&sxbf[r16][seg * 8] = *(int4*)u;
    }
    __syncthreads();

    // GEMM1: M=16, N=256 (wave -> 64 cols), K=128
    f32x4 acc1[4];
    #pragma unroll
    for (int nt = 0; nt < 4; ++nt) acc1[nt] = (f32x4){0.f, 0.f, 0.f, 0.f};
    #pragma unroll
    for (int kb = 0; kb < 4; ++kb) {
        bf16x8 afr = *(bf16x8*)&sxbf[l15][kb * 32 + quad * 8];
        #pragma unroll
        for (int nt = 0; nt < 4; ++nt) {
            int n = wv * 64 + nt * 16 + l15;
            bf16x8 bfr = *(const bf16x8*)(w1t + (long)n * DIM + kb * 32 + quad * 8);
            acc1[nt] = __builtin_amdgcn_mfma_f32_16x16x32_bf16(afr, bfr, acc1[nt], 0, 0, 0);
        }
    }
    // bias + gelu -> h_s (bf16)
    #pragma unroll
    for (int nt = 0; nt < 4; ++nt) {
        int col = wv * 64 + nt * 16 + l15;
        float bj = b1[col];
        #pragma unroll
        for (int r = 0; r < 4; ++r) {
            float hv = acc1[nt][r] + bj;
            hv = 0.5f * hv * (1.0f + erff(hv * 0.70710678118654752f));
            h_s[quad * 4 + r][col] = f2bf(hv);
        }
    }
    __syncthreads();

    // GEMM2: M=16, N=128 (wave -> 32 cols), K=256
    f32x4 acc2[2];
    acc2[0] = (f32x4){0.f, 0.f, 0.f, 0.f};
    acc2[1] = (f32x4){0.f, 0.f, 0.f, 0.f};
    #pragma unroll
    for (int kb = 0; kb < 8; ++kb) {
        bf16x8 afr = *(bf16x8*)&h_s[l15][kb * 32 + quad * 8];
        #pragma unroll
        for (int nt = 0; nt < 2; ++nt) {
            int n = wv * 32 + nt * 16 + l15;
            bf16x8 bfr = *(const bf16x8*)(w2t + (long)n * 256 + kb * 32 + quad * 8);
            acc2[nt] = __builtin_amdgcn_mfma_f32_16x16x32_bf16(afr, bfr, acc2[nt], 0, 0, 0);
        }
    }
    #pragma unroll
    for (int nt = 0; nt < 2; ++nt) {
        int col = wv * 32 + nt * 16 + l15;
        float bj = b2[col];
        #pragma unroll
        for (int r = 0; r < 4; ++r)
            o_s[quad * 4 + r][col] = acc2[nt][r] + bj;
    }
    __syncthreads();

    // LN(o) + residual (coalesced: 16 threads/row, 8 cols each)
    {
        float v[8];
        float s = 0.f, ss = 0.f;
        #pragma unroll
        for (int j = 0; j < 8; ++j) {
            v[j] = o_s[r16][seg * 8 + j];
            s += v[j]; ss += v[j] * v[j];
        }
        #pragma unroll
        for (int off = 1; off < 16; off <<= 1) {
            s  += __shfl_xor(s, off, 64);
            ss += __shfl_xor(ss, off, 64);
        }
        float mu = s * (1.0f / DIM);
        float var = fmaxf(ss * (1.0f / DIM) - mu * mu, 0.0f);
        float rstd = rsqrtf(var + EPS_LN);
        float* xr = x_out + (base + r16) * DIM + seg * 8;
        float4 x0 = *(const float4*)xr;
        float4 x1 = *(const float4*)(xr + 4);
        float4 g0 = *(const float4*)(ln_g + seg * 8);
        float4 g1 = *(const float4*)(ln_g + seg * 8 + 4);
        float4 c0 = *(const float4*)(ln_b + seg * 8);
        float4 c1 = *(const float4*)(ln_b + seg * 8 + 4);
        float4 o0, o1;
        o0.x = x0.x + (v[0] - mu) * rstd * g0.x + c0.x;
        o0.y = x0.y + (v[1] - mu) * rstd * g0.y + c0.y;
        o0.z = x0.z + (v[2] - mu) * rstd * g0.z + c0.z;
        o0.w = x0.w + (v[3] - mu) * rstd * g0.w + c0.w;
        o1.x = x1.x + (v[4] - mu) * rstd * g1.x + c1.x;
        o1.y = x1.y + (v[5] - mu) * rstd * g1.y + c1.y;
        o1.z = x1.z + (v[6] - mu) * rstd * g1.z + c1.z;
        o1.w = x1.w + (v[7] - mu) * rstd * g1.w + c1.w;
        *(float4*)xr = o0;
        *(float4*)(xr + 4) = o1;
    }
}

// ---------------------------------------------------------------------------
extern "C" void kernel_launch(void* const* d_in, const int* in_sizes, int n_in,
                              void* d_out, int out_size, void* d_ws, size_t ws_size,
                              hipStream_t stream) {
    const float* x        = (const float*)d_in[0];
    const float* conv_w   = (const float*)d_in[1];
    const float* q_w      = (const float*)d_in[2];
    const float* k_w      = (const float*)d_in[3];
    const float* v_w      = (const float*)d_in[4];
    const float* mlp_w1   = (const float*)d_in[5];
    const float* mlp_b1   = (const float*)d_in[6];
    const float* mlp_w2   = (const float*)d_in[7];
    const float* mlp_b2   = (const float*)d_in[8];
    const float* ln_in_g  = (const float*)d_in[9];
    const float* ln_in_b  = (const float*)d_in[10];
    const float* ln_out_g = (const float*)d_in[11];
    const float* ln_out_b = (const float*)d_in[12];
    const float* tau      = (const float*)d_in[13];
    const float* rpb      = (const float*)d_in[14];

    float* out_x    = (float*)d_out;
    float* out_attn = out_x + (long)BN * NPOS * DIM;
    float* out_acol = out_attn + (long)BN * 4 * NPOS * 9;

    char* ws = (char*)d_ws;
    float* k_g = (float*)ws;            ws += (long)BN * 4 * NPOS * DIM * 4;
    float* v_g = (float*)ws;            ws += (long)BN * 4 * NPOS * DIM * 4;
    float* seed = (float*)ws;           ws += (long)BN * NPOS * DIM * 4;
    unsigned short* x_bf = (unsigned short*)ws;
    float* qbuf = (float*)ws;           ws += (long)BN * NTOK * DIM * 2;   // qbuf aliases x_bf
    unsigned short* xln_bf = (unsigned short*)ws; ws += (long)BN * NTOK * DIM * 2;
    unsigned short* wt_conv = (unsigned short*)ws; ws += 1152L * DIM * 2;
    unsigned short* kwt = (unsigned short*)ws;     ws += (long)DIM * DIM * 2;
    unsigned short* vwt = (unsigned short*)ws;     ws += (long)DIM * DIM * 2;
    unsigned short* qwt = (unsigned short*)ws;     ws += (long)DIM * DIM * 2;
    unsigned short* w1t = (unsigned short*)ws;     ws += 256L * DIM * 2;
    unsigned short* w2t = (unsigned short*)ws;     ws += 256L * DIM * 2;
    float* col_sums = (float*)ws;       ws += (long)BN * NPOS * 4;

    prep_ln_kernel<<<16384, 256, 0, stream>>>(x, ln_in_g, ln_in_b, x_bf, xln_bf);
    conv_wt_kernel<<<dim3(128, 9), 128, 0, stream>>>(conv_w, wt_conv);
    wt_all_kernel<<<128, 128, 0, stream>>>(k_w, v_w, q_w, mlp_w1, mlp_w2,
                                           kwt, vwt, qwt, w1t, w2t);

    kv_mfma_kernel<<<1024, 256, 0, stream>>>(x_bf, xln_bf, kwt, vwt, k_g, v_g);
    conv_mfma_kernel<<<256, 256, 0, stream>>>(x_bf, wt_conv, seed);
    ln_kernel<<<BN * NPOS, 128, 0, stream>>>(seed, out_x, ln_out_g, ln_out_b);

    for (int it = 0; it < 3; ++it) {
        q_mfma_kernel<<<1024, 256, 0, stream>>>(out_x, qwt, ln_out_g, ln_out_b, qbuf);
        zero_kernel<<<(BN * NPOS + 255) / 256, 256, 0, stream>>>(col_sums, BN * NPOS);
        attn_kernel<<<16384, 256, 0, stream>>>(k_g, qbuf, rpb, tau, out_attn, col_sums);
        acol_upd_kernel<<<16384, 128, 0, stream>>>(out_attn, col_sums, v_g, out_acol, out_x);
        mlp_mfma_kernel<<<1024, 256, 0, stream>>>(out_x, w1t, w2t, mlp_b1, mlp_b2,
                                                  ln_out_g, ln_out_b);
    }
}